// Round 9
// baseline (83.386 us; speedup 1.0000x reference)
//
#include <hip/hip_runtime.h>
#include <hip/hip_bf16.h>

// B=4, S=4096, D=1024, H=64 single attention head.
// inputs fp32: x[4,4096,1024], Wq[1024,64], bq[64], Wk, bk, Wv, bv
// output fp32: [4,4096,64]

#define S_LEN 4096
#define D_MODEL 1024

typedef __attribute__((ext_vector_type(8))) short bf16x8;
typedef __attribute__((ext_vector_type(4))) float f32x4;
typedef __attribute__((ext_vector_type(16))) float f32x16;

__device__ inline short f2bf(float f) {
    union { float f; unsigned u; } v;
    v.f = f;
    unsigned r = v.u + 0x7fffu + ((v.u >> 16) & 1u);  // RNE
    return (short)(r >> 16);
}

__device__ inline unsigned cvt_pk(float lo, float hi) {
    unsigned r;
    asm("v_cvt_pk_bf16_f32 %0, %1, %2" : "=v"(r) : "v"(lo), "v"(hi));
    return r;
}

__device__ inline void pl32swap(unsigned& a, unsigned& b) {
    asm("v_permlane32_swap_b32 %0, %1" : "+v"(a), "+v"(b));
}

__device__ inline f32x16 fzero16() {
    f32x16 z;
#pragma unroll
    for (int i = 0; i < 16; ++i) z[i] = 0.f;
    return z;
}

// async global->LDS, 16B per lane, dest = lds_base + lane*16 (wave-uniform base)
__device__ inline void gload_lds16(const void* g, void* l) {
    __builtin_amdgcn_global_load_lds((const __attribute__((address_space(1))) void*)g,
                                     (__attribute__((address_space(3))) void*)l, 16, 0, 0);
}

// ---------------- kernel 1: W -> Wt bf16 [192][1024] via LDS transpose
__global__ void prep_w(const float* __restrict__ Wq, const float* __restrict__ Wk,
                       const float* __restrict__ Wv, short* __restrict__ Wt) {
    __shared__ short tile[64][72];
    int mat = blockIdx.x >> 4, kt = blockIdx.x & 15;
    const float* W = (mat == 0) ? Wq : (mat == 1 ? Wk : Wv);
    int tid = threadIdx.x;
    int h = tid & 63, kg = tid >> 6;
#pragma unroll
    for (int i = 0; i < 16; ++i) {
        int kl = kg * 16 + i;
        tile[h][kl] = f2bf(W[(size_t)(kt * 64 + kl) * 64 + h]);
    }
    __syncthreads();
    int h2 = tid >> 2, c = tid & 3;
    bf16x8 v0 = *(const bf16x8*)&tile[h2][c * 16];
    bf16x8 v1 = *(const bf16x8*)&tile[h2][c * 16 + 8];
    short* dst = Wt + (size_t)(mat * 64 + h2) * D_MODEL + kt * 64 + c * 16;
    *(bf16x8*)dst = v0;
    *(bf16x8*)(dst + 8) = v1;
}

// ---------------- kernel 2: QKV projection — triple-buffered LDS, raw barriers
// grid 512 x 256 threads (4 waves). Block = 32 rows x 192 cols, 16 BK=64 steps.
// Q outputs pre-scaled by log2(e)/sqrt(64) so attn softmax is exp2(s) directly.
__launch_bounds__(256)
__global__ void proj_kernel(const float* __restrict__ x, const short* __restrict__ Wt,
                            const float* __restrict__ bq, const float* __restrict__ bk,
                            const float* __restrict__ bv,
                            short* __restrict__ Qb, short* __restrict__ Kb,
                            short* __restrict__ Vt) {
    __shared__ __align__(16) char bsm[3 * 24576];    // Wt tile triple-buffer, 72 KB
    __shared__ short vsm[64][40];                    // V transpose staging, 5 KB
    const float CEXP = 0.18033688011112042f;         // log2(e)/sqrt(64)
    int w = threadIdx.x >> 6;
    int lane = threadIdx.x & 63;
    int g = lane >> 4, ln = lane & 15;
    int rt = w >> 1, nh = w & 1;
    int rowbase = blockIdx.x * 32;

    const char* WtB = (const char*)Wt;

    auto stageW = [&](int buf, int bk) {
#pragma unroll
        for (int i = 0; i < 6; ++i) {
            int od = w * 6144 + i * 1024 + lane * 16;
            int row = od >> 7, colb = od & 127;
            const char* src = WtB + (size_t)row * 2048 + bk * 128 + (colb ^ ((row & 7) << 4));
            gload_lds16(src, bsm + buf * 24576 + w * 6144 + i * 1024);
        }
    };

    f32x4 acc[6];
#pragma unroll
    for (int i = 0; i < 6; ++i) acc[i] = (f32x4){0.f, 0.f, 0.f, 0.f};

    const float* xw = x + (size_t)(rowbase + rt * 16 + ln) * D_MODEL + g * 8;

    stageW(0, 0);                                    // S(0): 6 loads
    stageW(1, 1);                                    // S(1): 6 loads
    f32x4 A0 = *(const f32x4*)(xw);                  // X(0): 4 loads
    f32x4 A1 = *(const f32x4*)(xw + 4);
    f32x4 A2 = *(const f32x4*)(xw + 32);
    f32x4 A3 = *(const f32x4*)(xw + 36);

    int jc = 0;
#pragma unroll 1
    for (int bk = 0; bk < 16; ++bk) {
        // wait tile bk (<=10 younger ops may remain: next stage 6 + next x 4)
        asm volatile("s_waitcnt vmcnt(10)" ::: "memory");
        __builtin_amdgcn_s_barrier();
        __builtin_amdgcn_sched_barrier(0);
        int js = jc + 2; if (js >= 3) js -= 3;
        stageW(js, (bk + 2) & 15);                   // redundant tail stages keep counts uniform
        f32x4 N0, N1, N2, N3;
        if (bk < 15) {
            const float* xn = xw + (bk + 1) * 64;
            N0 = *(const f32x4*)(xn);
            N1 = *(const f32x4*)(xn + 4);
            N2 = *(const f32x4*)(xn + 32);
            N3 = *(const f32x4*)(xn + 36);
        }
        const char* bs = bsm + jc * 24576;
        {
            union { bf16x8 v; unsigned u[4]; } A;
            A.u[0] = cvt_pk(A0[0], A0[1]);
            A.u[1] = cvt_pk(A0[2], A0[3]);
            A.u[2] = cvt_pk(A1[0], A1[1]);
            A.u[3] = cvt_pk(A1[2], A1[3]);
#pragma unroll
            for (int nt = 0; nt < 6; ++nt) {
                int row = nh * 96 + nt * 16 + ln;
                bf16x8 bfr = *(const bf16x8*)(bs + row * 128 + ((g * 16) ^ ((row & 7) << 4)));
                acc[nt] = __builtin_amdgcn_mfma_f32_16x16x32_bf16(A.v, bfr, acc[nt], 0, 0, 0);
            }
        }
        {
            union { bf16x8 v; unsigned u[4]; } A;
            A.u[0] = cvt_pk(A2[0], A2[1]);
            A.u[1] = cvt_pk(A2[2], A2[3]);
            A.u[2] = cvt_pk(A3[0], A3[1]);
            A.u[3] = cvt_pk(A3[2], A3[3]);
#pragma unroll
            for (int nt = 0; nt < 6; ++nt) {
                int row = nh * 96 + nt * 16 + ln;
                bf16x8 bfr = *(const bf16x8*)(bs + row * 128 + ((64 + g * 16) ^ ((row & 7) << 4)));
                acc[nt] = __builtin_amdgcn_mfma_f32_16x16x32_bf16(A.v, bfr, acc[nt], 0, 0, 0);
            }
        }
        if (bk < 15) { A0 = N0; A1 = N1; A2 = N2; A3 = N3; }
        jc = jc + 1; if (jc >= 3) jc = 0;
    }

    // epilogue: bias (+CEXP scale for Q) + writes. Global col c = nh*96 + nt*16 + ln.
#pragma unroll
    for (int nt = 0; nt < 6; ++nt) {
        int c = nh * 96 + nt * 16 + ln;
        int proj = c >> 6;
        int h = c & 63;
        float bias = (proj == 0 ? bq : (proj == 1 ? bk : bv))[h];
#pragma unroll
        for (int r = 0; r < 4; ++r) {
            int srow = rowbase + rt * 16 + g * 4 + r;
            float v = acc[nt][r] + bias;
            if (proj == 0) v *= CEXP;                // fold softmax scale into Q
            short hv = f2bf(v);
            if (proj == 0) {
                Qb[(size_t)srow * 64 + h] = hv;
            } else if (proj == 1) {
                Kb[(size_t)srow * 64 + h] = hv;
            } else {
                vsm[h][rt * 16 + g * 4 + r] = hv;
            }
        }
    }
    __syncthreads();
    {   // Vt writeout: thread = (h = t>>2, c = t&3)
        int t = threadIdx.x;
        int h = t >> 2, c = t & 3;
        bf16x8 val = *(const bf16x8*)&vsm[h][c * 8];
        int bb = rowbase >> 12;
        int sg = (rowbase & 4095) + c * 8;
        *(bf16x8*)(Vt + ((size_t)(bb * 64 + h) << 12) + sg) = val;
    }
}

// ---------------- kernel 3: flash attention — no-max softmax, shared staging,
// depth-2 prefetch, 1 raw barrier/iter. grid 256 (4b x 64 qsuper of 64 rows) x
// 512 threads (8 waves = 4 sp x 2 qt). Per sp: K/V triple-buffered (24 KB),
// qt0 wave stages K, qt1 stages V (4 loads each per 32-key tile).
__launch_bounds__(512)
__global__ void attn_kernel(const short* __restrict__ Qb, const short* __restrict__ Kb,
                            const short* __restrict__ Vt, float* __restrict__ out) {
    __shared__ __align__(16) char smraw[98304];      // 4 sp x (K 3x4KB | V 3x4KB)
    __shared__ float lsm[8 * 32];
    int lane = threadIdx.x & 63;
    int w = threadIdx.x >> 6;
    int l31 = lane & 31, hi = lane >> 5;
    int sp = w >> 1, qt = w & 1;

    int bid = blockIdx.x;
    int sb = (bid & 7) * 32 + (bid >> 3);            // XCD-bijective (256 % 8 == 0)
    int b = sb >> 6, qs = sb & 63;
    size_t qrow0 = ((size_t)b << 12) + (size_t)qs * 64;

    char* base = smraw + sp * 24576;
    const char* KB = (const char*)(Kb + (((size_t)b << 12) + sp * 1024) * 64);
    const char* VB = (const char*)Vt + (((size_t)b * 64) << 13) + (size_t)sp * 2048;

    auto stageT = [&](int buf, int t) {
        if (qt == 0) {                               // K tile: 32 keys x 128B
            char* dst = base + buf * 4096;
#pragma unroll
            for (int i = 0; i < 4; ++i) {
                int od = i * 1024 + lane * 16;
                int row = od >> 7, colb = od & 127;
                const char* src = KB + (size_t)(t * 32 + row) * 128 + (colb ^ ((row & 7) << 4));
                gload_lds16(src, dst + i * 1024);
            }
        } else {                                     // V tile: 64 h x 64B of keys
            char* dst = base + 12288 + buf * 4096;
#pragma unroll
            for (int i = 0; i < 4; ++i) {
                int od = i * 1024 + lane * 16;
                int row = od >> 6, colb = od & 63;
                const char* src = VB + (size_t)row * 8192 + t * 64 + (colb ^ ((row & 3) << 4));
                gload_lds16(src, dst + i * 1024);
            }
        }
    };

    // Q B-frags (pre-scaled by CEXP in proj): col q = l31, k-dim d
    bf16x8 qf[4];
    {
        const short* qp = Qb + (qrow0 + qt * 32 + l31) * 64 + hi * 8;
#pragma unroll
        for (int ks = 0; ks < 4; ++ks) qf[ks] = *(const bf16x8*)(qp + ks * 16);
    }
    asm volatile("s_waitcnt vmcnt(0)" ::: "memory"); // exact in-loop vmcnt counting

    f32x16 oacc0 = fzero16(), oacc1 = fzero16();     // O^T[h][q]
    float lacc[16];
#pragma unroll
    for (int r = 0; r < 16; ++r) lacc[r] = 0.f;

    stageT(0, 0);
    stageT(1, 1);

    int jc = 0;
#pragma unroll 1
    for (int t = 0; t < 32; ++t) {
        asm volatile("s_waitcnt vmcnt(4)" ::: "memory");   // tile t ready (t+1 in flight)
        __builtin_amdgcn_s_barrier();
        __builtin_amdgcn_sched_barrier(0);
        int js = jc + 2; if (js >= 3) js -= 3;
        stageT(js, (t + 2) & 31);                    // issue AFTER barrier (overwrite-safe)

        const char* kc = base + jc * 4096;
        const char* vc = base + 12288 + jc * 4096;

        // ---- K frags + QK^T (S^T: row = key 0..31, col = q = l31)
        bf16x8 kf[4];
#pragma unroll
        for (int ks = 0; ks < 4; ++ks)
            kf[ks] = *(const bf16x8*)(kc + l31 * 128 + ((ks * 32 + hi * 16) ^ ((l31 & 7) << 4)));
        f32x16 s0 = fzero16();
#pragma unroll
        for (int ks = 0; ks < 4; ++ks)
            s0 = __builtin_amdgcn_mfma_f32_32x32x16_bf16(kf[ks], qf[ks], s0, 0, 0, 0);

        // ---- V frags (A-operand: row = h, k = key)
        bf16x8 vf[4];
#pragma unroll
        for (int ht = 0; ht < 2; ++ht)
#pragma unroll
            for (int ks2 = 0; ks2 < 2; ++ks2)
                vf[ht * 2 + ks2] = *(const bf16x8*)(vc + (ht * 32 + l31) * 64
                                                    + ((ks2 * 32 + hi * 16) ^ ((l31 & 3) << 4)));

        // ---- no-max softmax: p = exp2(s) (Q pre-scaled); per-lane l accumulation
        float p[16];
#pragma unroll
        for (int r = 0; r < 16; ++r) p[r] = exp2f(s0[r]);
#pragma unroll
        for (int r = 0; r < 16; ++r) lacc[r] += p[r];

        // ---- pack P -> 2 bf16 B-frag tuples (keys 0-15, 16-31)
        unsigned D[8];
#pragma unroll
        for (int dw = 0; dw < 8; ++dw) D[dw] = cvt_pk(p[2 * dw], p[2 * dw + 1]);
        pl32swap(D[0], D[2]); pl32swap(D[1], D[3]);
        pl32swap(D[4], D[6]); pl32swap(D[5], D[7]);
        union { unsigned u[4]; bf16x8 v; } t0, t1;
        t0.u[0] = D[0]; t0.u[1] = D[1]; t0.u[2] = D[2]; t0.u[3] = D[3];
        t1.u[0] = D[4]; t1.u[1] = D[5]; t1.u[2] = D[6]; t1.u[3] = D[7];

        // ---- O += P V
        oacc0 = __builtin_amdgcn_mfma_f32_32x32x16_bf16(vf[0], t0.v, oacc0, 0, 0, 0);
        oacc1 = __builtin_amdgcn_mfma_f32_32x32x16_bf16(vf[2], t0.v, oacc1, 0, 0, 0);
        oacc0 = __builtin_amdgcn_mfma_f32_32x32x16_bf16(vf[1], t1.v, oacc0, 0, 0, 0);
        oacc1 = __builtin_amdgcn_mfma_f32_32x32x16_bf16(vf[3], t1.v, oacc1, 0, 0, 0);

        jc = jc + 1; if (jc >= 3) jc = 0;
    }

    // ---- final l per lane (q = l31): tree + one swap-half shuffle
    float lfin;
    {
        float lt[8];
#pragma unroll
        for (int r = 0; r < 8; ++r) lt[r] = lacc[r] + lacc[r + 8];
#pragma unroll
        for (int st = 4; st >= 1; st >>= 1)
#pragma unroll
            for (int r = 0; r < 4; ++r)
                if (r < st) lt[r] += lt[r + st];
        lfin = lt[0] + __shfl_xor(lt[0], 32);
    }

    // ---- merge partials across sp (pure sums — no max algebra)
    __syncthreads();                                 // full drain; then alias staging LDS
    float* osm = (float*)smraw;                      // [8 w][32 q][68]
    {
        float* ow = osm + (size_t)(w * 32 + l31) * 68;
#pragma unroll
        for (int r = 0; r < 16; ++r) {
            int h = (r & 3) + 8 * (r >> 2) + 4 * hi;
            ow[h] = oacc0[r];
            ow[32 + h] = oacc1[r];
        }
        if (hi == 0) lsm[w * 32 + l31] = lfin;
    }
    __syncthreads();
    {
        int tq = threadIdx.x >> 3, hb = (threadIdx.x & 7) * 8;
        int qt2 = tq >> 5, ql = tq & 31;
        f32x4 oa = (f32x4){0.f, 0.f, 0.f, 0.f}, ob = (f32x4){0.f, 0.f, 0.f, 0.f};
        float lsum = 0.f;
#pragma unroll
        for (int sp2 = 0; sp2 < 4; ++sp2) {
            int w2 = sp2 * 2 + qt2;
            lsum += lsm[w2 * 32 + ql];
            const float* src = osm + (size_t)(w2 * 32 + ql) * 68 + hb;
            f32x4 x0 = *(const f32x4*)src;
            f32x4 x1 = *(const f32x4*)(src + 4);
#pragma unroll
            for (int j = 0; j < 4; ++j) { oa[j] += x0[j]; ob[j] += x1[j]; }
        }
        float inv = 1.f / lsum;
        f32x4 r0, r1;
#pragma unroll
        for (int j = 0; j < 4; ++j) { r0[j] = oa[j] * inv; r1[j] = ob[j] * inv; }
        float* op = out + (qrow0 + tq) * 64 + hb;
        *(f32x4*)op = r0;
        *(f32x4*)(op + 4) = r1;
    }
}

extern "C" void kernel_launch(void* const* d_in, const int* in_sizes, int n_in,
                              void* d_out, int out_size, void* d_ws, size_t ws_size,
                              hipStream_t stream) {
    const float* x  = (const float*)d_in[0];
    const float* Wq = (const float*)d_in[1];
    const float* bq = (const float*)d_in[2];
    const float* Wk = (const float*)d_in[3];
    const float* bk = (const float*)d_in[4];
    const float* Wv = (const float*)d_in[5];
    const float* bv = (const float*)d_in[6];

    short* ws = (short*)d_ws;
    short* Wt = ws;                       // 192*1024
    short* Qb = Wt + 192 * 1024;          // 16384*64 (pre-scaled by log2(e)/8)
    short* Kb = Qb + 16384 * 64;
    short* Vt = Kb + 16384 * 64;          // [4][64][4096] transposed

    prep_w<<<48, 256, 0, stream>>>(Wq, Wk, Wv, Wt);
    proj_kernel<<<512, 256, 0, stream>>>(x, Wt, bq, bk, bv, Qb, Kb, Vt);
    attn_kernel<<<256, 512, 0, stream>>>(Qb, Kb, Vt, (float*)d_out);
}

// Round 10
// 65.882 us; speedup vs baseline: 1.2657x; 1.2657x over previous
//
#include <hip/hip_runtime.h>
#include <hip/hip_bf16.h>

// B=4, S=4096, D=1024, H=64 single attention head.
// inputs fp32: x[4,4096,1024], Wq[1024,64], bq[64], Wk, bk, Wv, bv
// output fp32: [4,4096,64]

#define S_LEN 4096
#define D_MODEL 1024

typedef __attribute__((ext_vector_type(8))) short bf16x8;
typedef __attribute__((ext_vector_type(4))) float f32x4;
typedef __attribute__((ext_vector_type(16))) float f32x16;

__device__ inline short f2bf(float f) {
    union { float f; unsigned u; } v;
    v.f = f;
    unsigned r = v.u + 0x7fffu + ((v.u >> 16) & 1u);  // RNE
    return (short)(r >> 16);
}

__device__ inline unsigned cvt_pk(float lo, float hi) {
    unsigned r;
    asm("v_cvt_pk_bf16_f32 %0, %1, %2" : "=v"(r) : "v"(lo), "v"(hi));
    return r;
}

__device__ inline void pl32swap(unsigned& a, unsigned& b) {
    asm("v_permlane32_swap_b32 %0, %1" : "+v"(a), "+v"(b));
}

__device__ inline f32x16 fzero16() {
    f32x16 z;
#pragma unroll
    for (int i = 0; i < 16; ++i) z[i] = 0.f;
    return z;
}

// async global->LDS, 16B per lane, dest = lds_base + lane*16 (wave-uniform base)
__device__ inline void gload_lds16(const void* g, void* l) {
    __builtin_amdgcn_global_load_lds((const __attribute__((address_space(1))) void*)g,
                                     (__attribute__((address_space(3))) void*)l, 16, 0, 0);
}

// ---------------- kernel 1: W -> Wt bf16 [192][1024] via LDS transpose
__global__ void prep_w(const float* __restrict__ Wq, const float* __restrict__ Wk,
                       const float* __restrict__ Wv, short* __restrict__ Wt) {
    __shared__ short tile[64][72];
    int mat = blockIdx.x >> 4, kt = blockIdx.x & 15;
    const float* W = (mat == 0) ? Wq : (mat == 1 ? Wk : Wv);
    int tid = threadIdx.x;
    int h = tid & 63, kg = tid >> 6;
#pragma unroll
    for (int i = 0; i < 16; ++i) {
        int kl = kg * 16 + i;
        tile[h][kl] = f2bf(W[(size_t)(kt * 64 + kl) * 64 + h]);
    }
    __syncthreads();
    int h2 = tid >> 2, c = tid & 3;
    bf16x8 v0 = *(const bf16x8*)&tile[h2][c * 16];
    bf16x8 v1 = *(const bf16x8*)&tile[h2][c * 16 + 8];
    short* dst = Wt + (size_t)(mat * 64 + h2) * D_MODEL + kt * 64 + c * 16;
    *(bf16x8*)dst = v0;
    *(bf16x8*)(dst + 8) = v1;
}

// ---------------- kernel 2: QKV projection (r8 double-buffer form + Q prescale)
// grid 512 x 256 threads (4 waves). Block = 32 rows x 192 cols, 16 BK=64 steps.
__launch_bounds__(256)
__global__ void proj_kernel(const float* __restrict__ x, const short* __restrict__ Wt,
                            const float* __restrict__ bq, const float* __restrict__ bk,
                            const float* __restrict__ bv,
                            short* __restrict__ Qb, short* __restrict__ Kb,
                            short* __restrict__ Vt) {
    __shared__ __align__(16) char bsm[2 * 24576];    // Wt tile dbuf, 48 KB
    __shared__ short vsm[64][40];                    // V transpose staging, 5 KB
    const float CEXP = 0.18033688011112042f;         // log2(e)/sqrt(64)
    int w = threadIdx.x >> 6;
    int lane = threadIdx.x & 63;
    int g = lane >> 4, ln = lane & 15;
    int rt = w >> 1, nh = w & 1;
    int rowbase = blockIdx.x * 32;

    const char* WtB = (const char*)Wt;

    auto stageW = [&](int buf, int bk) {
#pragma unroll
        for (int i = 0; i < 6; ++i) {
            int od = w * 6144 + i * 1024 + lane * 16;
            int row = od >> 7, colb = od & 127;
            const char* src = WtB + (size_t)row * 2048 + bk * 128 + (colb ^ ((row & 7) << 4));
            gload_lds16(src, bsm + buf * 24576 + w * 6144 + i * 1024);
        }
    };

    f32x4 acc[6];
#pragma unroll
    for (int i = 0; i < 6; ++i) acc[i] = (f32x4){0.f, 0.f, 0.f, 0.f};

    const float* xw = x + (size_t)(rowbase + rt * 16 + ln) * D_MODEL + g * 8;

    stageW(0, 0);
    f32x4 A0 = *(const f32x4*)(xw);
    f32x4 A1 = *(const f32x4*)(xw + 4);
    f32x4 A2 = *(const f32x4*)(xw + 32);
    f32x4 A3 = *(const f32x4*)(xw + 36);
    __syncthreads();

    int cur = 0;
#pragma unroll 1
    for (int bk = 0; bk < 16; ++bk) {
        f32x4 N0, N1, N2, N3;
        if (bk < 15) {
            const float* xn = xw + (bk + 1) * 64;
            N0 = *(const f32x4*)(xn);
            N1 = *(const f32x4*)(xn + 4);
            N2 = *(const f32x4*)(xn + 32);
            N3 = *(const f32x4*)(xn + 36);
            stageW(cur ^ 1, bk + 1);
        }
        const char* bs = bsm + cur * 24576;
        {
            union { bf16x8 v; unsigned u[4]; } A;
            A.u[0] = cvt_pk(A0[0], A0[1]);
            A.u[1] = cvt_pk(A0[2], A0[3]);
            A.u[2] = cvt_pk(A1[0], A1[1]);
            A.u[3] = cvt_pk(A1[2], A1[3]);
#pragma unroll
            for (int nt = 0; nt < 6; ++nt) {
                int row = nh * 96 + nt * 16 + ln;
                bf16x8 bfr = *(const bf16x8*)(bs + row * 128 + ((g * 16) ^ ((row & 7) << 4)));
                acc[nt] = __builtin_amdgcn_mfma_f32_16x16x32_bf16(A.v, bfr, acc[nt], 0, 0, 0);
            }
        }
        {
            union { bf16x8 v; unsigned u[4]; } A;
            A.u[0] = cvt_pk(A2[0], A2[1]);
            A.u[1] = cvt_pk(A2[2], A2[3]);
            A.u[2] = cvt_pk(A3[0], A3[1]);
            A.u[3] = cvt_pk(A3[2], A3[3]);
#pragma unroll
            for (int nt = 0; nt < 6; ++nt) {
                int row = nh * 96 + nt * 16 + ln;
                bf16x8 bfr = *(const bf16x8*)(bs + row * 128 + ((64 + g * 16) ^ ((row & 7) << 4)));
                acc[nt] = __builtin_amdgcn_mfma_f32_16x16x32_bf16(A.v, bfr, acc[nt], 0, 0, 0);
            }
        }
        __syncthreads();
        if (bk < 15) { A0 = N0; A1 = N1; A2 = N2; A3 = N3; }
        cur ^= 1;
    }

    // epilogue: bias (+CEXP for Q) + writes. Global col c = nh*96 + nt*16 + ln.
#pragma unroll
    for (int nt = 0; nt < 6; ++nt) {
        int c = nh * 96 + nt * 16 + ln;
        int proj = c >> 6;
        int h = c & 63;
        float bias = (proj == 0 ? bq : (proj == 1 ? bk : bv))[h];
#pragma unroll
        for (int r = 0; r < 4; ++r) {
            int srow = rowbase + rt * 16 + g * 4 + r;
            float v = acc[nt][r] + bias;
            if (proj == 0) v *= CEXP;                // fold softmax scale into Q
            short hv = f2bf(v);
            if (proj == 0) {
                Qb[(size_t)srow * 64 + h] = hv;
            } else if (proj == 1) {
                Kb[(size_t)srow * 64 + h] = hv;
            } else {
                vsm[h][rt * 16 + g * 4 + r] = hv;
            }
        }
    }
    __syncthreads();
    {   // Vt writeout: thread = (h = t>>2, c = t&3)
        int t = threadIdx.x;
        int h = t >> 2, c = t & 3;
        bf16x8 val = *(const bf16x8*)&vsm[h][c * 8];
        int bb = rowbase >> 12;
        int sg = (rowbase & 4095) + c * 8;
        *(bf16x8*)(Vt + ((size_t)(bb * 64 + h) << 12) + sg) = val;
    }
}

// ---------------- kernel 3: flash attention — 64-key tiles, 1 barrier/iter,
// double-buffered K and V, no-max softmax.
// grid 256 (4b x 64 qsuper of 64 rows) x 512 threads (8 waves = 4 sp x 2 qt).
// qt0 wave stages K (8 loads/tile), qt1 stages V. 128 KB LDS -> 1 block/CU.
__launch_bounds__(512)
__global__ void attn_kernel(const short* __restrict__ Qb, const short* __restrict__ Kb,
                            const short* __restrict__ Vt, float* __restrict__ out) {
    __shared__ __align__(16) char smraw[131072];     // 4 sp x (K 2x8KB | V 2x8KB)
    __shared__ float lsm[256];
    int lane = threadIdx.x & 63;
    int w = threadIdx.x >> 6;
    int l31 = lane & 31, hi = lane >> 5;
    int sp = w >> 1, qt = w & 1;

    int bid = blockIdx.x;
    int sb = (bid & 7) * 32 + (bid >> 3);            // XCD-bijective (256 % 8 == 0)
    int b = sb >> 6, qs = sb & 63;
    size_t qrow0 = ((size_t)b << 12) + (size_t)qs * 64;

    char* base = smraw + sp * 32768;
    char* kbuf = base;                               // 2 x 8KB
    char* vbuf = base + 16384;                       // 2 x 8KB

    const char* KB = (const char*)(Kb + (((size_t)b << 12) + sp * 1024) * 64);
    const char* VB = (const char*)Vt + (((size_t)b * 64) << 13) + (size_t)sp * 2048;

    // tile = 64 keys. K tile: [64 keys][128B d]; V tile: [64 h][128B keys]. Both
    // staged with row-XOR pre-swizzled source; 8 gload instrs each (8 rows/instr,
    // fully-consumed 128B lines).
    auto stageT = [&](int buf, int t) {
        if (qt == 0) {
            char* dst = kbuf + buf * 8192;
#pragma unroll
            for (int i = 0; i < 8; ++i) {
                int od = i * 1024 + lane * 16;
                int row = od >> 7, colb = od & 127;
                const char* src = KB + (size_t)(t * 64 + row) * 128 + (colb ^ ((row & 7) << 4));
                gload_lds16(src, dst + i * 1024);
            }
        } else {
            char* dst = vbuf + buf * 8192;
#pragma unroll
            for (int i = 0; i < 8; ++i) {
                int od = i * 1024 + lane * 16;
                int row = od >> 7, colb = od & 127;
                const char* src = VB + (size_t)row * 8192 + t * 128 + (colb ^ ((row & 7) << 4));
                gload_lds16(src, dst + i * 1024);
            }
        }
    };

    // Q B-frags (pre-scaled by CEXP in proj): col q = l31, k-dim d
    bf16x8 qf[4];
    {
        const short* qp = Qb + (qrow0 + qt * 32 + l31) * 64 + hi * 8;
#pragma unroll
        for (int ks = 0; ks < 4; ++ks) qf[ks] = *(const bf16x8*)(qp + ks * 16);
    }

    f32x16 oacc0 = fzero16(), oacc1 = fzero16();     // O^T[h][q]
    float lacc[16];
#pragma unroll
    for (int r = 0; r < 16; ++r) lacc[r] = 0.f;

    int swz = (l31 & 7) << 4;
    stageT(0, 0);

#pragma unroll 1
    for (int t = 0; t < 16; ++t) {
        // drain own loads (stage(t), issued one full compute phase ago -> cheap),
        // then barrier: every wave's tile t is now in LDS.
        asm volatile("s_waitcnt vmcnt(0)" ::: "memory");
        __builtin_amdgcn_s_barrier();
        __builtin_amdgcn_sched_barrier(0);
        if (t < 15) stageT((t + 1) & 1, t + 1);      // other buffer: overwrite-safe

        const char* kc = kbuf + (t & 1) * 8192;
        const char* vc = vbuf + (t & 1) * 8192;

        // ---- K frags + QK^T (S^T: row = key, col = q = l31)
        bf16x8 kf[8];
#pragma unroll
        for (int kt = 0; kt < 2; ++kt)
#pragma unroll
            for (int ks = 0; ks < 4; ++ks)
                kf[kt * 4 + ks] = *(const bf16x8*)(kc + (kt * 32 + l31) * 128
                                                  + ((ks * 32 + hi * 16) ^ swz));
        f32x16 s0 = fzero16(), s1 = fzero16();
#pragma unroll
        for (int ks = 0; ks < 4; ++ks) {
            s0 = __builtin_amdgcn_mfma_f32_32x32x16_bf16(kf[ks], qf[ks], s0, 0, 0, 0);
            s1 = __builtin_amdgcn_mfma_f32_32x32x16_bf16(kf[4 + ks], qf[ks], s1, 0, 0, 0);
        }

        // ---- V frags (A-operand: row = h, k = key)
        bf16x8 vf[8];
#pragma unroll
        for (int ht = 0; ht < 2; ++ht)
#pragma unroll
            for (int kk = 0; kk < 4; ++kk)
                vf[ht * 4 + kk] = *(const bf16x8*)(vc + (ht * 32 + l31) * 128
                                                   + ((kk * 32 + hi * 16) ^ swz));

        // ---- no-max softmax: p = exp2(s); per-lane l accumulation
        float p0[16], p1[16];
#pragma unroll
        for (int r = 0; r < 16; ++r) p0[r] = exp2f(s0[r]);
#pragma unroll
        for (int r = 0; r < 16; ++r) p1[r] = exp2f(s1[r]);
#pragma unroll
        for (int r = 0; r < 16; ++r) lacc[r] += p0[r] + p1[r];

        // ---- pack P -> 4 bf16 B-frag tuples (keys 0-15,16-31,32-47,48-63)
        union { unsigned u[4]; bf16x8 v; } t00, t01, t10, t11;
        {
            unsigned D[8];
#pragma unroll
            for (int dw = 0; dw < 8; ++dw) D[dw] = cvt_pk(p0[2 * dw], p0[2 * dw + 1]);
            pl32swap(D[0], D[2]); pl32swap(D[1], D[3]);
            pl32swap(D[4], D[6]); pl32swap(D[5], D[7]);
            t00.u[0] = D[0]; t00.u[1] = D[1]; t00.u[2] = D[2]; t00.u[3] = D[3];
            t01.u[0] = D[4]; t01.u[1] = D[5]; t01.u[2] = D[6]; t01.u[3] = D[7];
        }
        {
            unsigned D[8];
#pragma unroll
            for (int dw = 0; dw < 8; ++dw) D[dw] = cvt_pk(p1[2 * dw], p1[2 * dw + 1]);
            pl32swap(D[0], D[2]); pl32swap(D[1], D[3]);
            pl32swap(D[4], D[6]); pl32swap(D[5], D[7]);
            t10.u[0] = D[0]; t10.u[1] = D[1]; t10.u[2] = D[2]; t10.u[3] = D[3];
            t11.u[0] = D[4]; t11.u[1] = D[5]; t11.u[2] = D[6]; t11.u[3] = D[7];
        }

        // ---- O += P V
        oacc0 = __builtin_amdgcn_mfma_f32_32x32x16_bf16(vf[0], t00.v, oacc0, 0, 0, 0);
        oacc1 = __builtin_amdgcn_mfma_f32_32x32x16_bf16(vf[4], t00.v, oacc1, 0, 0, 0);
        oacc0 = __builtin_amdgcn_mfma_f32_32x32x16_bf16(vf[1], t01.v, oacc0, 0, 0, 0);
        oacc1 = __builtin_amdgcn_mfma_f32_32x32x16_bf16(vf[5], t01.v, oacc1, 0, 0, 0);
        oacc0 = __builtin_amdgcn_mfma_f32_32x32x16_bf16(vf[2], t10.v, oacc0, 0, 0, 0);
        oacc1 = __builtin_amdgcn_mfma_f32_32x32x16_bf16(vf[6], t10.v, oacc1, 0, 0, 0);
        oacc0 = __builtin_amdgcn_mfma_f32_32x32x16_bf16(vf[3], t11.v, oacc0, 0, 0, 0);
        oacc1 = __builtin_amdgcn_mfma_f32_32x32x16_bf16(vf[7], t11.v, oacc1, 0, 0, 0);
    }

    // ---- final l per lane (q = l31): tree + one swap-half shuffle
    float lfin;
    {
        float lt[8];
#pragma unroll
        for (int r = 0; r < 8; ++r) lt[r] = lacc[r] + lacc[r + 8];
#pragma unroll
        for (int st = 4; st >= 1; st >>= 1)
#pragma unroll
            for (int r = 0; r < 4; ++r)
                if (r < st) lt[r] += lt[r + st];
        lfin = lt[0] + __shfl_xor(lt[0], 32);
    }

    // ---- merge partials across sp (pure sums)
    __syncthreads();                                 // all compute done; alias staging LDS
    float* osm = (float*)smraw;                      // [8 w][32 q][68]
    {
        float* ow = osm + (size_t)(w * 32 + l31) * 68;
#pragma unroll
        for (int r = 0; r < 16; ++r) {
            int h = (r & 3) + 8 * (r >> 2) + 4 * hi;
            ow[h] = oacc0[r];
            ow[32 + h] = oacc1[r];
        }
        if (hi == 0) lsm[w * 32 + l31] = lfin;
    }
    __syncthreads();
    {
        int tq = threadIdx.x >> 3, hb = (threadIdx.x & 7) * 8;
        int qt2 = tq >> 5, ql = tq & 31;
        f32x4 oa = (f32x4){0.f, 0.f, 0.f, 0.f}, ob = (f32x4){0.f, 0.f, 0.f, 0.f};
        float lsum = 0.f;
#pragma unroll
        for (int sp2 = 0; sp2 < 4; ++sp2) {
            int w2 = sp2 * 2 + qt2;
            lsum += lsm[w2 * 32 + ql];
            const float* src = osm + (size_t)(w2 * 32 + ql) * 68 + hb;
            f32x4 x0 = *(const f32x4*)src;
            f32x4 x1 = *(const f32x4*)(src + 4);
#pragma unroll
            for (int j = 0; j < 4; ++j) { oa[j] += x0[j]; ob[j] += x1[j]; }
        }
        float inv = 1.f / lsum;
        f32x4 r0, r1;
#pragma unroll
        for (int j = 0; j < 4; ++j) { r0[j] = oa[j] * inv; r1[j] = ob[j] * inv; }
        float* op = out + (qrow0 + tq) * 64 + hb;
        *(f32x4*)op = r0;
        *(f32x4*)(op + 4) = r1;
    }
}

extern "C" void kernel_launch(void* const* d_in, const int* in_sizes, int n_in,
                              void* d_out, int out_size, void* d_ws, size_t ws_size,
                              hipStream_t stream) {
    const float* x  = (const float*)d_in[0];
    const float* Wq = (const float*)d_in[1];
    const float* bq = (const float*)d_in[2];
    const float* Wk = (const float*)d_in[3];
    const float* bk = (const float*)d_in[4];
    const float* Wv = (const float*)d_in[5];
    const float* bv = (const float*)d_in[6];

    short* ws = (short*)d_ws;
    short* Wt = ws;                       // 192*1024
    short* Qb = Wt + 192 * 1024;          // 16384*64 (pre-scaled by log2(e)/8)
    short* Kb = Qb + 16384 * 64;
    short* Vt = Kb + 16384 * 64;          // [4][64][4096] transposed

    prep_w<<<48, 256, 0, stream>>>(Wq, Wk, Wv, Wt);
    proj_kernel<<<512, 256, 0, stream>>>(x, Wt, bq, bk, bv, Qb, Kb, Vt);
    attn_kernel<<<256, 512, 0, stream>>>(Qb, Kb, Vt, (float*)d_out);
}